// Round 6
// baseline (730.278 us; speedup 1.0000x reference)
//
#include <hip/hip_runtime.h>
#include <math.h>

// GCN via CSR gather: build CSR(dst) once (src-only 4B payload), then
// 3x (GEMM[+fused relu] -> per-node gather-agg) -> mean-pool(+count+relu) -> head -> softmax.
// N=100000 nodes, E=1.6M edges (+N self-loops folded into gather init), nhid=64, 64 graphs.

__global__ void deg_init_kernel(int* __restrict__ deg, int N) {
    int i = blockIdx.x * 256 + threadIdx.x;
    if (i < N) deg[i] = 1;  // self-loop contributes 1 to every node's degree
}

__global__ void deg_count_kernel(const int* __restrict__ dst, int* __restrict__ deg, int E) {
    int e = blockIdx.x * 256 + threadIdx.x;
    if (e < E) atomicAdd(&deg[dst[e]], 1);
}

__global__ void dinv_kernel(const int* __restrict__ deg, float* __restrict__ dinv, int N) {
    int i = blockIdx.x * 256 + threadIdx.x;
    if (i < N) dinv[i] = rsqrtf((float)deg[i]);  // deg >= 1 always (self-loop)
}

// ---- CSR build: counting sort of edges by dst ----
// cdeg[i] = deg[i]-1 (real in-edges). rowptr = exclusive scan(cdeg).

__global__ void block_sum_kernel(const int* __restrict__ deg, int* __restrict__ bsum, int N) {
    int i = blockIdx.x * 256 + threadIdx.x;
    int v = (i < N) ? deg[i] - 1 : 0;
    for (int off = 32; off; off >>= 1) v += __shfl_down(v, off, 64);
    __shared__ int s[4];
    if ((threadIdx.x & 63) == 0) s[threadIdx.x >> 6] = v;
    __syncthreads();
    if (threadIdx.x == 0) bsum[blockIdx.x] = s[0] + s[1] + s[2] + s[3];
}

// single block: exclusive scan of bsum[nb], nb <= 512
__global__ void scan_bsum_kernel(int* __restrict__ bsum, int nb) {
    __shared__ int s[512];
    int t = threadIdx.x;
    s[t] = (t < nb) ? bsum[t] : 0;
    __syncthreads();
    for (int off = 1; off < 512; off <<= 1) {
        int v = (t >= off) ? s[t - off] : 0;
        __syncthreads();
        s[t] += v;
        __syncthreads();
    }
    if (t < nb) bsum[t] = (t == 0) ? 0 : s[t - 1];
}

__global__ void rowptr_kernel(const int* __restrict__ deg, const int* __restrict__ bsum,
                              int* __restrict__ rowptr, int* __restrict__ cursor, int N) {
    __shared__ int s[256];
    int t = threadIdx.x;
    int i = blockIdx.x * 256 + t;
    int v = (i < N) ? deg[i] - 1 : 0;
    s[t] = v;
    __syncthreads();
    for (int off = 1; off < 256; off <<= 1) {
        int u = (t >= off) ? s[t - off] : 0;
        __syncthreads();
        s[t] += u;
        __syncthreads();
    }
    int excl = s[t] - v + bsum[blockIdx.x];
    if (i < N) { rowptr[i] = excl; cursor[i] = excl; }
    if (i == N - 1) rowptr[N] = excl + v;  // = E
}

// csr[pos] = src  (4B payload; weight recomputed in gather as dinv[src]*dinv[node]).
// Non-temporal store: scattered 4B writes can't line-merge in L2 anyway (R4/R5
// evidence: ~100MB HBM writes = E x 64B full-line evictions), so bypass L2
// allocation and write through as sectors.
__global__ void fill_kernel(const int* __restrict__ src, const int* __restrict__ dst,
                            int* __restrict__ cursor, int* __restrict__ csr, int E) {
    int e = blockIdx.x * 256 + threadIdx.x;
    if (e < E) {
        int s = src[e], d = dst[e];
        int pos = atomicAdd(&cursor[d], 1);
        __builtin_nontemporal_store(s, &csr[pos]);
    }
}

// H[N,64] = relu?(X)[N,FIN] @ W[FIN,64]; 16 rows per block, W + X tile staged in LDS.
template <int FIN, bool RELU>
__global__ __launch_bounds__(256) void gemm_kernel(const float* __restrict__ X,
                                                   const float* __restrict__ W,
                                                   float* __restrict__ H, int N) {
    __shared__ float sW[FIN * 64];
    __shared__ float sX[16 * FIN];
    int tid = threadIdx.x;
    for (int i = tid * 4; i < FIN * 64; i += 1024)
        *(float4*)&sW[i] = *(const float4*)&W[i];
    int rowBase = blockIdx.x * 16;
    for (int i = tid * 4; i < 16 * FIN; i += 1024) {
        int r = i / FIN, c = i - r * FIN;
        int gr = rowBase + r;
        float4 v = make_float4(0.f, 0.f, 0.f, 0.f);
        if (gr < N) {
            v = *(const float4*)&X[(long)gr * FIN + c];
            if (RELU) {
                v.x = fmaxf(v.x, 0.f); v.y = fmaxf(v.y, 0.f);
                v.z = fmaxf(v.z, 0.f); v.w = fmaxf(v.w, 0.f);
            }
        }
        *(float4*)&sX[i] = v;
    }
    __syncthreads();
    int col = tid & 63, rsub = tid >> 6;
#pragma unroll
    for (int rr = 0; rr < 4; ++rr) {
        int r = rr * 4 + rsub;
        int gr = rowBase + r;
        if (gr < N) {
            float acc = 0.f;
#pragma unroll 16
            for (int k = 0; k < FIN; ++k)
                acc = fmaf(sX[r * FIN + k], sW[k * 64 + col], acc);
            H[(long)gr * 64 + col] = acc;
        }
    }
}

// One wave per dst node, lane = feature column. acc starts with bias + self-loop term.
// csr holds src only; w = dinv[src]*dinv[node] (dst==node in CSR-by-dst). csr and
// dinv reads are wave-uniform broadcasts. Unroll x4 with independent partials for ILP.
__global__ __launch_bounds__(256) void gather_kernel(const int* __restrict__ csr,
                                                     const int* __restrict__ rowptr,
                                                     const float* __restrict__ h,
                                                     const float* __restrict__ dinv,
                                                     const float* __restrict__ b,
                                                     float* __restrict__ agg, int N) {
    int node = (blockIdx.x * 256 + threadIdx.x) >> 6;
    int lane = threadIdx.x & 63;
    if (node >= N) return;
    int beg = rowptr[node], end = rowptr[node + 1];
    float di = dinv[node];
    float a0 = fmaf(di * di, h[(long)node * 64 + lane], b[lane]);
    float a1 = 0.f, a2 = 0.f, a3 = 0.f;
    int e = beg;
    for (; e + 4 <= end; e += 4) {
        int s0 = csr[e], s1 = csr[e + 1], s2 = csr[e + 2], s3 = csr[e + 3];
        float w0 = dinv[s0] * di, w1 = dinv[s1] * di, w2 = dinv[s2] * di, w3 = dinv[s3] * di;
        a0 = fmaf(w0, h[(long)s0 * 64 + lane], a0);
        a1 = fmaf(w1, h[(long)s1 * 64 + lane], a1);
        a2 = fmaf(w2, h[(long)s2 * 64 + lane], a2);
        a3 = fmaf(w3, h[(long)s3 * 64 + lane], a3);
    }
    for (; e < end; ++e) {
        int s0 = csr[e];
        a0 = fmaf(dinv[s0] * di, h[(long)s0 * 64 + lane], a0);
    }
    agg[(long)node * 64 + lane] = (a0 + a1) + (a2 + a3);
}

__global__ void zero_kernel(float* __restrict__ a, int n) {
    int i = blockIdx.x * 256 + threadIdx.x;
    if (i < n) a[i] = 0.f;
}

// batch is sorted: one WAVE per 64 contiguous nodes (lane = col), running accumulation
// with flush on graph change. col==0 lane also flushes run-length counts. Fused
// layer-3 ReLU on load.
__global__ __launch_bounds__(256) void pool_kernel(const float* __restrict__ h,
                                                   const int* __restrict__ batch,
                                                   float* __restrict__ sums,
                                                   float* __restrict__ cnts, int N) {
    int col = threadIdx.x & 63;
    int wave = threadIdx.x >> 6;
    int base = blockIdx.x * 256 + wave * 64;   // this wave's 64-node span
    float acc = 0.f, cnt = 0.f;
    int curg = -1;
    for (int j = 0; j < 64; ++j) {
        int node = base + j;
        if (node >= N) break;
        int g = batch[node];                    // wave-uniform (scalar load)
        if (g != curg) {
            if (curg >= 0) {
                atomicAdd(&sums[curg * 64 + col], acc);
                if (col == 0) atomicAdd(&cnts[curg], cnt);
            }
            acc = 0.f; cnt = 0.f;
            curg = g;
        }
        acc += fmaxf(h[(long)node * 64 + col], 0.f);
        cnt += 1.f;
    }
    if (curg >= 0) {
        atomicAdd(&sums[curg * 64 + col], acc);
        if (col == 0) atomicAdd(&cnts[curg], cnt);
    }
}

// One thread per graph: pooled = sums/cnt, logits = pooled @ Wl + bl, softmax.
__global__ void final_kernel(const float* __restrict__ sums, const float* __restrict__ cnts,
                             const float* __restrict__ Wl, const float* __restrict__ bl,
                             float* __restrict__ out, int G) {
    int g = blockIdx.x * blockDim.x + threadIdx.x;
    if (g >= G) return;
    float inv = 1.0f / fmaxf(cnts[g], 1.0f);
    float logits[10];
#pragma unroll
    for (int k = 0; k < 10; ++k) logits[k] = bl[k];
    for (int c = 0; c < 64; ++c) {
        float p = sums[g * 64 + c] * inv;
#pragma unroll
        for (int k = 0; k < 10; ++k) logits[k] = fmaf(p, Wl[c * 10 + k], logits[k]);
    }
    float m = logits[0];
#pragma unroll
    for (int k = 1; k < 10; ++k) m = fmaxf(m, logits[k]);
    float se = 0.f;
#pragma unroll
    for (int k = 0; k < 10; ++k) { logits[k] = expf(logits[k] - m); se += logits[k]; }
    float is = 1.0f / se;
#pragma unroll
    for (int k = 0; k < 10; ++k) out[g * 10 + k] = logits[k] * is;
}

extern "C" void kernel_launch(void* const* d_in, const int* in_sizes, int n_in,
                              void* d_out, int out_size, void* d_ws, size_t ws_size,
                              hipStream_t stream) {
    const float* x    = (const float*)d_in[0];
    const int* edges  = (const int*)d_in[1];
    const int* batch  = (const int*)d_in[2];
    const float* W1   = (const float*)d_in[3];
    const float* b1   = (const float*)d_in[4];
    const float* W2   = (const float*)d_in[5];
    const float* b2   = (const float*)d_in[6];
    const float* W3   = (const float*)d_in[7];
    const float* b3   = (const float*)d_in[8];
    const float* Wl   = (const float*)d_in[9];
    const float* bl   = (const float*)d_in[10];

    const int N = in_sizes[0] / 128;   // 100000
    const int E = in_sizes[1] / 2;     // 1600000
    const int G = out_size / 10;       // 64
    const int* src = edges;
    const int* dst = edges + E;

    float* ws     = (float*)d_ws;
    float* h      = ws;                           // N*64
    float* agg    = ws + (size_t)N * 64;          // N*64
    int*   csr    = (int*)(ws + (size_t)2 * N * 64);  // E ints (src per slot)
    float* dinv   = ws + (size_t)2 * N * 64 + (size_t)E;  // N
    int*   deg    = (int*)(dinv + N);             // N
    int*   rowptr = deg + N;                      // N+1
    int*   cursor = rowptr + N + 1;               // N
    int*   bsum   = cursor + N;                   // <=512
    float* sums   = (float*)(bsum + 512);         // G*64
    float* cnts   = sums + (size_t)G * 64;        // G

    const int gemmGrid = (N + 15) / 16;
    const int gatherGrid = (N + 3) / 4;           // 4 waves (nodes) per 256-thread block
    const int nb = (N + 255) / 256;               // 391 <= 512

    // degree + normalization (layer-invariant)
    deg_init_kernel<<<(N + 255) / 256, 256, 0, stream>>>(deg, N);
    deg_count_kernel<<<(E + 255) / 256, 256, 0, stream>>>(dst, deg, E);
    dinv_kernel<<<(N + 255) / 256, 256, 0, stream>>>(deg, dinv, N);

    // CSR build (counting sort by dst), reused by all 3 layers
    block_sum_kernel<<<nb, 256, 0, stream>>>(deg, bsum, N);
    scan_bsum_kernel<<<1, 512, 0, stream>>>(bsum, nb);
    rowptr_kernel<<<nb, 256, 0, stream>>>(deg, bsum, rowptr, cursor, N);
    fill_kernel<<<(E + 255) / 256, 256, 0, stream>>>(src, dst, cursor, csr, E);

    // layer 1: x[N,128] @ W1 -> h; gather (self-loop + bias folded in)
    gemm_kernel<128, false><<<gemmGrid, 256, 0, stream>>>(x, W1, h, N);
    gather_kernel<<<gatherGrid, 256, 0, stream>>>(csr, rowptr, h, dinv, b1, agg, N);

    // layer 2 (relu of layer-1 output fused into gemm's X load)
    gemm_kernel<64, true><<<gemmGrid, 256, 0, stream>>>(agg, W2, h, N);
    gather_kernel<<<gatherGrid, 256, 0, stream>>>(csr, rowptr, h, dinv, b2, agg, N);

    // layer 3
    gemm_kernel<64, true><<<gemmGrid, 256, 0, stream>>>(agg, W3, h, N);
    gather_kernel<<<gatherGrid, 256, 0, stream>>>(csr, rowptr, h, dinv, b3, agg, N);

    // mean-pool per graph (+count, +fused relu) + head + softmax
    zero_kernel<<<(G * 65 + 255) / 256, 256, 0, stream>>>(sums, G * 65);
    pool_kernel<<<(N + 255) / 256, 256, 0, stream>>>(agg, batch, sums, cnts, N);
    final_kernel<<<1, 64, 0, stream>>>(sums, cnts, Wl, bl, (float*)d_out, G);
}

// Round 7
// 632.706 us; speedup vs baseline: 1.1542x; 1.1542x over previous
//
#include <hip/hip_runtime.h>
#include <math.h>

// GCN via CSR gather. CSR(dst) built with a two-level binned counting sort so all
// scattered writes happen in block-private windows (R4-R6 evidence: device-wide
// scattered 4-8B stores cost a full 64B line eviction each -> ~100MB for a 6.4MB
// payload). Then 3x (GEMM[+fused relu] -> per-node gather-agg) -> mean-pool -> head.
// N=100000 nodes, E=1.6M edges (+N self-loops folded into gather init), nhid=64.

__global__ void deg_init_kernel(int* __restrict__ deg, int N) {
    int i = blockIdx.x * 256 + threadIdx.x;
    if (i < N) deg[i] = 1;  // self-loop contributes 1 to every node's degree
}

__global__ void deg_count_kernel(const int* __restrict__ dst, int* __restrict__ deg, int E) {
    int e = blockIdx.x * 256 + threadIdx.x;
    if (e < E) atomicAdd(&deg[dst[e]], 1);
}

__global__ void dinv_kernel(const int* __restrict__ deg, float* __restrict__ dinv, int N) {
    int i = blockIdx.x * 256 + threadIdx.x;
    if (i < N) dinv[i] = rsqrtf((float)deg[i]);  // deg >= 1 always (self-loop)
}

// ---- rowptr = exclusive scan of (deg-1) ----

__global__ void block_sum_kernel(const int* __restrict__ deg, int* __restrict__ bsum, int N) {
    int i = blockIdx.x * 256 + threadIdx.x;
    int v = (i < N) ? deg[i] - 1 : 0;
    for (int off = 32; off; off >>= 1) v += __shfl_down(v, off, 64);
    __shared__ int s[4];
    if ((threadIdx.x & 63) == 0) s[threadIdx.x >> 6] = v;
    __syncthreads();
    if (threadIdx.x == 0) bsum[blockIdx.x] = s[0] + s[1] + s[2] + s[3];
}

__global__ void scan_bsum_kernel(int* __restrict__ bsum, int nb) {
    __shared__ int s[512];
    int t = threadIdx.x;
    s[t] = (t < nb) ? bsum[t] : 0;
    __syncthreads();
    for (int off = 1; off < 512; off <<= 1) {
        int v = (t >= off) ? s[t - off] : 0;
        __syncthreads();
        s[t] += v;
        __syncthreads();
    }
    if (t < nb) bsum[t] = (t == 0) ? 0 : s[t - 1];
}

__global__ void rowptr_kernel(const int* __restrict__ deg, const int* __restrict__ bsum,
                              int* __restrict__ rowptr, int N) {
    __shared__ int s[256];
    int t = threadIdx.x;
    int i = blockIdx.x * 256 + t;
    int v = (i < N) ? deg[i] - 1 : 0;
    s[t] = v;
    __syncthreads();
    for (int off = 1; off < 256; off <<= 1) {
        int u = (t >= off) ? s[t - off] : 0;
        __syncthreads();
        s[t] += u;
        __syncthreads();
    }
    int excl = s[t] - v + bsum[blockIdx.x];
    if (i < N) rowptr[i] = excl;
    if (i == N - 1) rowptr[N] = excl + v;  // = E
}

// ---- binned counting sort: partition = dst>>9 (512 nodes), P<=256, B=256 chunks ----

// Phase A: counts[p][b] = #edges in chunk b with dst in partition p.
__global__ __launch_bounds__(256) void hist_kernel(const int* __restrict__ dst,
                                                   int* __restrict__ counts,
                                                   int E, int P, int C) {
    __shared__ int hist[256];
    int t = threadIdx.x, b = blockIdx.x;
    if (t < P) hist[t] = 0;
    __syncthreads();
    int beg = b * C, end = min(E, beg + C);
    for (int e = beg + t; e < end; e += 256)
        atomicAdd(&hist[dst[e] >> 9], 1);
    __syncthreads();
    if (t < P) counts[t * 256 + b] = hist[t];
}

// Phase B: offs[p][b] = rowptr[p*512] + exclusive-prefix over chunks of counts[p][*].
// (binned shares csr's global indexing: partition base comes straight from rowptr.)
__global__ __launch_bounds__(256) void offs_kernel(const int* __restrict__ counts,
                                                   const int* __restrict__ rowptr,
                                                   int* __restrict__ offs) {
    __shared__ int s[256];
    int t = threadIdx.x, p = blockIdx.x;
    int v = counts[p * 256 + t];
    s[t] = v;
    __syncthreads();
    for (int off = 1; off < 256; off <<= 1) {
        int u = (t >= off) ? s[t - off] : 0;
        __syncthreads();
        s[t] += u;
        __syncthreads();
    }
    offs[p * 256 + t] = rowptr[p << 9] + s[t] - v;
}

// Phase C: route edges to per-(block,partition) CONTIGUOUS runs (~24 edges = 192B of
// plain stores each) via LDS cursors -> ~10B/edge HBM writes instead of 64B/edge.
__global__ __launch_bounds__(256) void bin_kernel(const int* __restrict__ src,
                                                  const int* __restrict__ dst,
                                                  const int* __restrict__ offs,
                                                  int2* __restrict__ binned,
                                                  int E, int P, int C) {
    __shared__ int cur[256];
    int t = threadIdx.x, b = blockIdx.x;
    if (t < P) cur[t] = offs[t * 256 + b];
    __syncthreads();
    int beg = b * C, end = min(E, beg + C);
    for (int e = beg + t; e < end; e += 256) {
        int d = dst[e], s = src[e];
        int pos = atomicAdd(&cur[d >> 9], 1);
        binned[pos] = make_int2(s, d);
    }
}

// Phase D: one block per partition; stream the partition's binned segment (coalesced)
// and counting-sort by dst into the partition's ~33KB csr slice. All scattered stores
// target ONE CU's L2 window (~100KB working set) -> full line merging.
__global__ __launch_bounds__(256) void lsort_kernel(const int2* __restrict__ binned,
                                                    const int* __restrict__ rowptr,
                                                    int* __restrict__ csr, int N) {
    __shared__ int cur[512];
    int t = threadIdx.x, p = blockIdx.x;
    int lo = p << 9, hi = min(N, lo + 512);
    for (int i = t; i < hi - lo; i += 256) cur[i] = rowptr[lo + i];
    __syncthreads();
    int eBeg = rowptr[lo], eEnd = rowptr[hi];  // rowptr[N] = E covers the last partition
    for (int j = eBeg + t; j < eEnd; j += 256) {
        int2 sd = binned[j];
        int pos = atomicAdd(&cur[sd.y - lo], 1);
        csr[pos] = sd.x;
    }
}

// H[N,64] = relu?(X)[N,FIN] @ W[FIN,64]; 16 rows per block, W + X tile staged in LDS.
template <int FIN, bool RELU>
__global__ __launch_bounds__(256) void gemm_kernel(const float* __restrict__ X,
                                                   const float* __restrict__ W,
                                                   float* __restrict__ H, int N) {
    __shared__ float sW[FIN * 64];
    __shared__ float sX[16 * FIN];
    int tid = threadIdx.x;
    for (int i = tid * 4; i < FIN * 64; i += 1024)
        *(float4*)&sW[i] = *(const float4*)&W[i];
    int rowBase = blockIdx.x * 16;
    for (int i = tid * 4; i < 16 * FIN; i += 1024) {
        int r = i / FIN, c = i - r * FIN;
        int gr = rowBase + r;
        float4 v = make_float4(0.f, 0.f, 0.f, 0.f);
        if (gr < N) {
            v = *(const float4*)&X[(long)gr * FIN + c];
            if (RELU) {
                v.x = fmaxf(v.x, 0.f); v.y = fmaxf(v.y, 0.f);
                v.z = fmaxf(v.z, 0.f); v.w = fmaxf(v.w, 0.f);
            }
        }
        *(float4*)&sX[i] = v;
    }
    __syncthreads();
    int col = tid & 63, rsub = tid >> 6;
#pragma unroll
    for (int rr = 0; rr < 4; ++rr) {
        int r = rr * 4 + rsub;
        int gr = rowBase + r;
        if (gr < N) {
            float acc = 0.f;
#pragma unroll 16
            for (int k = 0; k < FIN; ++k)
                acc = fmaf(sX[r * FIN + k], sW[k * 64 + col], acc);
            H[(long)gr * 64 + col] = acc;
        }
    }
}

// One wave per dst node, lane = feature column. acc starts with bias + self-loop term.
// csr holds src only; w = dinv[src]*dinv[node]. Unroll x4, independent partials for ILP.
__global__ __launch_bounds__(256) void gather_kernel(const int* __restrict__ csr,
                                                     const int* __restrict__ rowptr,
                                                     const float* __restrict__ h,
                                                     const float* __restrict__ dinv,
                                                     const float* __restrict__ b,
                                                     float* __restrict__ agg, int N) {
    int node = (blockIdx.x * 256 + threadIdx.x) >> 6;
    int lane = threadIdx.x & 63;
    if (node >= N) return;
    int beg = rowptr[node], end = rowptr[node + 1];
    float di = dinv[node];
    float a0 = fmaf(di * di, h[(long)node * 64 + lane], b[lane]);
    float a1 = 0.f, a2 = 0.f, a3 = 0.f;
    int e = beg;
    for (; e + 4 <= end; e += 4) {
        int s0 = csr[e], s1 = csr[e + 1], s2 = csr[e + 2], s3 = csr[e + 3];
        float w0 = dinv[s0] * di, w1 = dinv[s1] * di, w2 = dinv[s2] * di, w3 = dinv[s3] * di;
        a0 = fmaf(w0, h[(long)s0 * 64 + lane], a0);
        a1 = fmaf(w1, h[(long)s1 * 64 + lane], a1);
        a2 = fmaf(w2, h[(long)s2 * 64 + lane], a2);
        a3 = fmaf(w3, h[(long)s3 * 64 + lane], a3);
    }
    for (; e < end; ++e) {
        int s0 = csr[e];
        a0 = fmaf(dinv[s0] * di, h[(long)s0 * 64 + lane], a0);
    }
    agg[(long)node * 64 + lane] = (a0 + a1) + (a2 + a3);
}

__global__ void zero_kernel(float* __restrict__ a, int n) {
    int i = blockIdx.x * 256 + threadIdx.x;
    if (i < n) a[i] = 0.f;
}

// batch is sorted: one WAVE per 64 contiguous nodes (lane = col), running accumulation
// with flush on graph change; col==0 lane flushes run-length counts; fused relu.
__global__ __launch_bounds__(256) void pool_kernel(const float* __restrict__ h,
                                                   const int* __restrict__ batch,
                                                   float* __restrict__ sums,
                                                   float* __restrict__ cnts, int N) {
    int col = threadIdx.x & 63;
    int wave = threadIdx.x >> 6;
    int base = blockIdx.x * 256 + wave * 64;
    float acc = 0.f, cnt = 0.f;
    int curg = -1;
    for (int j = 0; j < 64; ++j) {
        int node = base + j;
        if (node >= N) break;
        int g = batch[node];
        if (g != curg) {
            if (curg >= 0) {
                atomicAdd(&sums[curg * 64 + col], acc);
                if (col == 0) atomicAdd(&cnts[curg], cnt);
            }
            acc = 0.f; cnt = 0.f;
            curg = g;
        }
        acc += fmaxf(h[(long)node * 64 + col], 0.f);
        cnt += 1.f;
    }
    if (curg >= 0) {
        atomicAdd(&sums[curg * 64 + col], acc);
        if (col == 0) atomicAdd(&cnts[curg], cnt);
    }
}

// One thread per graph: pooled = sums/cnt, logits = pooled @ Wl + bl, softmax.
__global__ void final_kernel(const float* __restrict__ sums, const float* __restrict__ cnts,
                             const float* __restrict__ Wl, const float* __restrict__ bl,
                             float* __restrict__ out, int G) {
    int g = blockIdx.x * blockDim.x + threadIdx.x;
    if (g >= G) return;
    float inv = 1.0f / fmaxf(cnts[g], 1.0f);
    float logits[10];
#pragma unroll
    for (int k = 0; k < 10; ++k) logits[k] = bl[k];
    for (int c = 0; c < 64; ++c) {
        float p = sums[g * 64 + c] * inv;
#pragma unroll
        for (int k = 0; k < 10; ++k) logits[k] = fmaf(p, Wl[c * 10 + k], logits[k]);
    }
    float m = logits[0];
#pragma unroll
    for (int k = 1; k < 10; ++k) m = fmaxf(m, logits[k]);
    float se = 0.f;
#pragma unroll
    for (int k = 0; k < 10; ++k) { logits[k] = expf(logits[k] - m); se += logits[k]; }
    float is = 1.0f / se;
#pragma unroll
    for (int k = 0; k < 10; ++k) out[g * 10 + k] = logits[k] * is;
}

extern "C" void kernel_launch(void* const* d_in, const int* in_sizes, int n_in,
                              void* d_out, int out_size, void* d_ws, size_t ws_size,
                              hipStream_t stream) {
    const float* x    = (const float*)d_in[0];
    const int* edges  = (const int*)d_in[1];
    const int* batch  = (const int*)d_in[2];
    const float* W1   = (const float*)d_in[3];
    const float* b1   = (const float*)d_in[4];
    const float* W2   = (const float*)d_in[5];
    const float* b2   = (const float*)d_in[6];
    const float* W3   = (const float*)d_in[7];
    const float* b3   = (const float*)d_in[8];
    const float* Wl   = (const float*)d_in[9];
    const float* bl   = (const float*)d_in[10];

    const int N = in_sizes[0] / 128;   // 100000
    const int E = in_sizes[1] / 2;     // 1600000
    const int G = out_size / 10;       // 64
    const int* src = edges;
    const int* dst = edges + E;

    float* ws     = (float*)d_ws;
    float* h      = ws;                           // N*64 floats
    float* agg    = ws + (size_t)N * 64;          // N*64 floats
    int2*  binned = (int2*)h;                     // E int2 (12.8MB) ALIASES h: dead before gemm1
    int*   csr    = (int*)(ws + (size_t)2 * N * 64);  // E ints
    float* dinv   = (float*)(csr + E);            // N
    int*   deg    = (int*)(dinv + N);             // N
    int*   rowptr = deg + N;                      // N+1
    int*   counts = rowptr + N + 1;               // P*256 <= 65536
    int*   offs   = counts + 256 * 256;           // P*256
    int*   bsum   = offs + 256 * 256;             // <=512
    float* sums   = (float*)(bsum + 512);         // G*64
    float* cnts   = sums + (size_t)G * 64;        // G

    const int gemmGrid = (N + 15) / 16;
    const int gatherGrid = (N + 3) / 4;           // 4 waves (nodes) per 256-thread block
    const int nb = (N + 255) / 256;               // 391 <= 512
    const int P = (N + 511) >> 9;                 // 196 partitions of 512 nodes
    const int C = (E + 255) / 256;                // edges per chunk (256 chunks)

    // degree + normalization (layer-invariant)
    deg_init_kernel<<<(N + 255) / 256, 256, 0, stream>>>(deg, N);
    deg_count_kernel<<<(E + 255) / 256, 256, 0, stream>>>(dst, deg, E);
    dinv_kernel<<<(N + 255) / 256, 256, 0, stream>>>(deg, dinv, N);

    // rowptr (exclusive scan of in-degrees)
    block_sum_kernel<<<nb, 256, 0, stream>>>(deg, bsum, N);
    scan_bsum_kernel<<<1, 512, 0, stream>>>(bsum, nb);
    rowptr_kernel<<<nb, 256, 0, stream>>>(deg, bsum, rowptr, N);

    // binned counting sort -> csr (src per slot), reused by all 3 layers
    hist_kernel<<<256, 256, 0, stream>>>(dst, counts, E, P, C);
    offs_kernel<<<P, 256, 0, stream>>>(counts, rowptr, offs);
    bin_kernel<<<256, 256, 0, stream>>>(src, dst, offs, binned, E, P, C);
    lsort_kernel<<<P, 256, 0, stream>>>(binned, rowptr, csr, N);

    // layer 1: x[N,128] @ W1 -> h (overwrites binned; build is complete); gather
    gemm_kernel<128, false><<<gemmGrid, 256, 0, stream>>>(x, W1, h, N);
    gather_kernel<<<gatherGrid, 256, 0, stream>>>(csr, rowptr, h, dinv, b1, agg, N);

    // layer 2 (relu of layer-1 output fused into gemm's X load)
    gemm_kernel<64, true><<<gemmGrid, 256, 0, stream>>>(agg, W2, h, N);
    gather_kernel<<<gatherGrid, 256, 0, stream>>>(csr, rowptr, h, dinv, b2, agg, N);

    // layer 3
    gemm_kernel<64, true><<<gemmGrid, 256, 0, stream>>>(agg, W3, h, N);
    gather_kernel<<<gatherGrid, 256, 0, stream>>>(csr, rowptr, h, dinv, b3, agg, N);

    // mean-pool per graph (+count, +fused relu) + head + softmax
    zero_kernel<<<(G * 65 + 255) / 256, 256, 0, stream>>>(sums, G * 65);
    pool_kernel<<<(N + 255) / 256, 256, 0, stream>>>(agg, batch, sums, cnts, N);
    final_kernel<<<1, 64, 0, stream>>>(sums, cnts, Wl, bl, (float*)d_out, G);
}

// Round 8
// 546.597 us; speedup vs baseline: 1.3360x; 1.1575x over previous
//
#include <hip/hip_runtime.h>
#include <math.h>

// GCN via CSR gather. CSR(dst) built with a two-level binned counting sort (all
// scattered writes in block-private windows; R4-R6: device-wide scattered stores
// cost a full 64B line each). 3x (register-tiled GEMM[+fused relu] -> gather-agg)
// -> mean-pool(+count+relu) -> head -> softmax.
// N=100000 nodes, E=1.6M edges (+N self-loops folded into gather init), nhid=64.

__global__ void deg_init_kernel(int* __restrict__ deg, int N) {
    int i = blockIdx.x * 256 + threadIdx.x;
    if (i < N) deg[i] = 1;  // self-loop contributes 1 to every node's degree
}

__global__ void deg_count_kernel(const int* __restrict__ dst, int* __restrict__ deg, int E) {
    int e = blockIdx.x * 256 + threadIdx.x;
    if (e < E) atomicAdd(&deg[dst[e]], 1);
}

__global__ void dinv_kernel(const int* __restrict__ deg, float* __restrict__ dinv, int N) {
    int i = blockIdx.x * 256 + threadIdx.x;
    if (i < N) dinv[i] = rsqrtf((float)deg[i]);  // deg >= 1 always (self-loop)
}

// ---- rowptr = exclusive scan of (deg-1) ----

__global__ void block_sum_kernel(const int* __restrict__ deg, int* __restrict__ bsum, int N) {
    int i = blockIdx.x * 256 + threadIdx.x;
    int v = (i < N) ? deg[i] - 1 : 0;
    for (int off = 32; off; off >>= 1) v += __shfl_down(v, off, 64);
    __shared__ int s[4];
    if ((threadIdx.x & 63) == 0) s[threadIdx.x >> 6] = v;
    __syncthreads();
    if (threadIdx.x == 0) bsum[blockIdx.x] = s[0] + s[1] + s[2] + s[3];
}

__global__ void scan_bsum_kernel(int* __restrict__ bsum, int nb) {
    __shared__ int s[512];
    int t = threadIdx.x;
    s[t] = (t < nb) ? bsum[t] : 0;
    __syncthreads();
    for (int off = 1; off < 512; off <<= 1) {
        int v = (t >= off) ? s[t - off] : 0;
        __syncthreads();
        s[t] += v;
        __syncthreads();
    }
    if (t < nb) bsum[t] = (t == 0) ? 0 : s[t - 1];
}

__global__ void rowptr_kernel(const int* __restrict__ deg, const int* __restrict__ bsum,
                              int* __restrict__ rowptr, int N) {
    __shared__ int s[256];
    int t = threadIdx.x;
    int i = blockIdx.x * 256 + t;
    int v = (i < N) ? deg[i] - 1 : 0;
    s[t] = v;
    __syncthreads();
    for (int off = 1; off < 256; off <<= 1) {
        int u = (t >= off) ? s[t - off] : 0;
        __syncthreads();
        s[t] += u;
        __syncthreads();
    }
    int excl = s[t] - v + bsum[blockIdx.x];
    if (i < N) rowptr[i] = excl;
    if (i == N - 1) rowptr[N] = excl + v;  // = E
}

// ---- binned counting sort: partition = dst>>9 (512 nodes), P<=256, 256 chunks ----

__global__ __launch_bounds__(256) void hist_kernel(const int* __restrict__ dst,
                                                   int* __restrict__ counts,
                                                   int E, int P, int C) {
    __shared__ int hist[256];
    int t = threadIdx.x, b = blockIdx.x;
    if (t < P) hist[t] = 0;
    __syncthreads();
    int beg = b * C, end = min(E, beg + C);
    for (int e = beg + t; e < end; e += 256)
        atomicAdd(&hist[dst[e] >> 9], 1);
    __syncthreads();
    if (t < P) counts[t * 256 + b] = hist[t];
}

__global__ __launch_bounds__(256) void offs_kernel(const int* __restrict__ counts,
                                                   const int* __restrict__ rowptr,
                                                   int* __restrict__ offs) {
    __shared__ int s[256];
    int t = threadIdx.x, p = blockIdx.x;
    int v = counts[p * 256 + t];
    s[t] = v;
    __syncthreads();
    for (int off = 1; off < 256; off <<= 1) {
        int u = (t >= off) ? s[t - off] : 0;
        __syncthreads();
        s[t] += u;
        __syncthreads();
    }
    offs[p * 256 + t] = rowptr[p << 9] + s[t] - v;
}

__global__ __launch_bounds__(256) void bin_kernel(const int* __restrict__ src,
                                                  const int* __restrict__ dst,
                                                  const int* __restrict__ offs,
                                                  int2* __restrict__ binned,
                                                  int E, int P, int C) {
    __shared__ int cur[256];
    int t = threadIdx.x, b = blockIdx.x;
    if (t < P) cur[t] = offs[t * 256 + b];
    __syncthreads();
    int beg = b * C, end = min(E, beg + C);
    for (int e = beg + t; e < end; e += 256) {
        int d = dst[e], s = src[e];
        int pos = atomicAdd(&cur[d >> 9], 1);
        binned[pos] = make_int2(s, d);
    }
}

__global__ __launch_bounds__(256) void lsort_kernel(const int2* __restrict__ binned,
                                                    const int* __restrict__ rowptr,
                                                    int* __restrict__ csr, int N) {
    __shared__ int cur[512];
    int t = threadIdx.x, p = blockIdx.x;
    int lo = p << 9, hi = min(N, lo + 512);
    for (int i = t; i < hi - lo; i += 256) cur[i] = rowptr[lo + i];
    __syncthreads();
    int eBeg = rowptr[lo], eEnd = rowptr[hi];
    for (int j = eBeg + t; j < eEnd; j += 256) {
        int2 sd = binned[j];
        int pos = atomicAdd(&cur[sd.y - lo], 1);
        csr[pos] = sd.x;
    }
}

// H[N,64] = relu?(X)[N,FIN] @ W[FIN,64]. Register-tiled: 64x64 tile/block, each of
// 256 threads computes 4x4 outputs (rows ty+16*rr, cols 4*tx). Per k-chunk of 4:
// 8 ds_read_b128 for 64 FMAs (was 1 ds_read_b32 per FMA -> LDS-issue-bound at
// VALUBusy 31%). sX leading dim padded +4: row stride 128 floats is pow-2, the 4
// distinct row reads would 4-way bank-conflict (1.58x, m136); +4 staggers banks.
template <int FIN, bool RELU>
__global__ __launch_bounds__(256) void gemm_kernel(const float* __restrict__ X,
                                                   const float* __restrict__ W,
                                                   float* __restrict__ H, int N) {
    constexpr int FINP = FIN + 4;
    __shared__ float sW[FIN * 64];
    __shared__ float sX[64 * FINP];
    int tid = threadIdx.x;
    for (int i = tid * 4; i < FIN * 64; i += 1024)
        *(float4*)&sW[i] = *(const float4*)&W[i];
    int rowBase = blockIdx.x * 64;
    for (int i = tid * 4; i < 64 * FIN; i += 1024) {
        int r = i / FIN, c = i - r * FIN;
        int gr = rowBase + r;
        float4 v = make_float4(0.f, 0.f, 0.f, 0.f);
        if (gr < N) {
            v = *(const float4*)&X[(long)gr * FIN + c];
            if (RELU) {
                v.x = fmaxf(v.x, 0.f); v.y = fmaxf(v.y, 0.f);
                v.z = fmaxf(v.z, 0.f); v.w = fmaxf(v.w, 0.f);
            }
        }
        *(float4*)&sX[r * FINP + c] = v;
    }
    __syncthreads();
    int tx = tid & 15;   // col group: 4*tx .. 4*tx+3
    int ty = tid >> 4;   // rows ty + 16*rr
    float acc[4][4];
#pragma unroll
    for (int rr = 0; rr < 4; ++rr)
#pragma unroll
        for (int cc = 0; cc < 4; ++cc) acc[rr][cc] = 0.f;
    for (int k = 0; k < FIN; k += 4) {
        float xr[4][4], wr[4][4];
#pragma unroll
        for (int rr = 0; rr < 4; ++rr)
            *(float4*)xr[rr] = *(const float4*)&sX[(ty + 16 * rr) * FINP + k];
#pragma unroll
        for (int kk = 0; kk < 4; ++kk)
            *(float4*)wr[kk] = *(const float4*)&sW[(k + kk) * 64 + 4 * tx];
#pragma unroll
        for (int rr = 0; rr < 4; ++rr)
#pragma unroll
            for (int kk = 0; kk < 4; ++kk)
#pragma unroll
                for (int cc = 0; cc < 4; ++cc)
                    acc[rr][cc] = fmaf(xr[rr][kk], wr[kk][cc], acc[rr][cc]);
    }
#pragma unroll
    for (int rr = 0; rr < 4; ++rr) {
        int gr = rowBase + ty + 16 * rr;
        if (gr < N)
            *(float4*)&H[(long)gr * 64 + 4 * tx] =
                make_float4(acc[rr][0], acc[rr][1], acc[rr][2], acc[rr][3]);
    }
}

// One wave per dst node, lane = feature column. acc starts with bias + self-loop term.
// csr holds src only; w = dinv[src]*dinv[node]. Unroll x4, independent partials for ILP.
__global__ __launch_bounds__(256) void gather_kernel(const int* __restrict__ csr,
                                                     const int* __restrict__ rowptr,
                                                     const float* __restrict__ h,
                                                     const float* __restrict__ dinv,
                                                     const float* __restrict__ b,
                                                     float* __restrict__ agg, int N) {
    int node = (blockIdx.x * 256 + threadIdx.x) >> 6;
    int lane = threadIdx.x & 63;
    if (node >= N) return;
    int beg = rowptr[node], end = rowptr[node + 1];
    float di = dinv[node];
    float a0 = fmaf(di * di, h[(long)node * 64 + lane], b[lane]);
    float a1 = 0.f, a2 = 0.f, a3 = 0.f;
    int e = beg;
    for (; e + 4 <= end; e += 4) {
        int s0 = csr[e], s1 = csr[e + 1], s2 = csr[e + 2], s3 = csr[e + 3];
        float w0 = dinv[s0] * di, w1 = dinv[s1] * di, w2 = dinv[s2] * di, w3 = dinv[s3] * di;
        a0 = fmaf(w0, h[(long)s0 * 64 + lane], a0);
        a1 = fmaf(w1, h[(long)s1 * 64 + lane], a1);
        a2 = fmaf(w2, h[(long)s2 * 64 + lane], a2);
        a3 = fmaf(w3, h[(long)s3 * 64 + lane], a3);
    }
    for (; e < end; ++e) {
        int s0 = csr[e];
        a0 = fmaf(dinv[s0] * di, h[(long)s0 * 64 + lane], a0);
    }
    agg[(long)node * 64 + lane] = (a0 + a1) + (a2 + a3);
}

__global__ void zero_kernel(float* __restrict__ a, int n) {
    int i = blockIdx.x * 256 + threadIdx.x;
    if (i < n) a[i] = 0.f;
}

// batch is sorted: one WAVE per 64 contiguous nodes (lane = col), running accumulation
// with flush on graph change; col==0 lane flushes run-length counts; fused relu.
__global__ __launch_bounds__(256) void pool_kernel(const float* __restrict__ h,
                                                   const int* __restrict__ batch,
                                                   float* __restrict__ sums,
                                                   float* __restrict__ cnts, int N) {
    int col = threadIdx.x & 63;
    int wave = threadIdx.x >> 6;
    int base = blockIdx.x * 256 + wave * 64;
    float acc = 0.f, cnt = 0.f;
    int curg = -1;
    for (int j = 0; j < 64; ++j) {
        int node = base + j;
        if (node >= N) break;
        int g = batch[node];
        if (g != curg) {
            if (curg >= 0) {
                atomicAdd(&sums[curg * 64 + col], acc);
                if (col == 0) atomicAdd(&cnts[curg], cnt);
            }
            acc = 0.f; cnt = 0.f;
            curg = g;
        }
        acc += fmaxf(h[(long)node * 64 + col], 0.f);
        cnt += 1.f;
    }
    if (curg >= 0) {
        atomicAdd(&sums[curg * 64 + col], acc);
        if (col == 0) atomicAdd(&cnts[curg], cnt);
    }
}

// One thread per graph: pooled = sums/cnt, logits = pooled @ Wl + bl, softmax.
__global__ void final_kernel(const float* __restrict__ sums, const float* __restrict__ cnts,
                             const float* __restrict__ Wl, const float* __restrict__ bl,
                             float* __restrict__ out, int G) {
    int g = blockIdx.x * blockDim.x + threadIdx.x;
    if (g >= G) return;
    float inv = 1.0f / fmaxf(cnts[g], 1.0f);
    float logits[10];
#pragma unroll
    for (int k = 0; k < 10; ++k) logits[k] = bl[k];
    for (int c = 0; c < 64; ++c) {
        float p = sums[g * 64 + c] * inv;
#pragma unroll
        for (int k = 0; k < 10; ++k) logits[k] = fmaf(p, Wl[c * 10 + k], logits[k]);
    }
    float m = logits[0];
#pragma unroll
    for (int k = 1; k < 10; ++k) m = fmaxf(m, logits[k]);
    float se = 0.f;
#pragma unroll
    for (int k = 0; k < 10; ++k) { logits[k] = expf(logits[k] - m); se += logits[k]; }
    float is = 1.0f / se;
#pragma unroll
    for (int k = 0; k < 10; ++k) out[g * 10 + k] = logits[k] * is;
}

extern "C" void kernel_launch(void* const* d_in, const int* in_sizes, int n_in,
                              void* d_out, int out_size, void* d_ws, size_t ws_size,
                              hipStream_t stream) {
    const float* x    = (const float*)d_in[0];
    const int* edges  = (const int*)d_in[1];
    const int* batch  = (const int*)d_in[2];
    const float* W1   = (const float*)d_in[3];
    const float* b1   = (const float*)d_in[4];
    const float* W2   = (const float*)d_in[5];
    const float* b2   = (const float*)d_in[6];
    const float* W3   = (const float*)d_in[7];
    const float* b3   = (const float*)d_in[8];
    const float* Wl   = (const float*)d_in[9];
    const float* bl   = (const float*)d_in[10];

    const int N = in_sizes[0] / 128;   // 100000
    const int E = in_sizes[1] / 2;     // 1600000
    const int G = out_size / 10;       // 64
    const int* src = edges;
    const int* dst = edges + E;

    float* ws     = (float*)d_ws;
    float* h      = ws;                           // N*64 floats
    float* agg    = ws + (size_t)N * 64;          // N*64 floats
    int2*  binned = (int2*)h;                     // E int2 ALIASES h: dead before gemm1
    int*   csr    = (int*)(ws + (size_t)2 * N * 64);  // E ints
    float* dinv   = (float*)(csr + E);            // N
    int*   deg    = (int*)(dinv + N);             // N
    int*   rowptr = deg + N;                      // N+1
    int*   counts = rowptr + N + 1;               // 256*256
    int*   offs   = counts + 256 * 256;           // 256*256
    int*   bsum   = offs + 256 * 256;             // <=512
    float* sums   = (float*)(bsum + 512);         // G*64
    float* cnts   = sums + (size_t)G * 64;        // G

    const int gemmGrid = (N + 63) / 64;
    const int gatherGrid = (N + 3) / 4;
    const int nb = (N + 255) / 256;               // 391 <= 512
    const int P = (N + 511) >> 9;                 // 196 partitions of 512 nodes
    const int C = (E + 255) / 256;                // edges per chunk (256 chunks)

    // degree + normalization (layer-invariant)
    deg_init_kernel<<<(N + 255) / 256, 256, 0, stream>>>(deg, N);
    deg_count_kernel<<<(E + 255) / 256, 256, 0, stream>>>(dst, deg, E);
    dinv_kernel<<<(N + 255) / 256, 256, 0, stream>>>(deg, dinv, N);

    // rowptr (exclusive scan of in-degrees)
    block_sum_kernel<<<nb, 256, 0, stream>>>(deg, bsum, N);
    scan_bsum_kernel<<<1, 512, 0, stream>>>(bsum, nb);
    rowptr_kernel<<<nb, 256, 0, stream>>>(deg, bsum, rowptr, N);

    // binned counting sort -> csr (src per slot), reused by all 3 layers
    hist_kernel<<<256, 256, 0, stream>>>(dst, counts, E, P, C);
    offs_kernel<<<P, 256, 0, stream>>>(counts, rowptr, offs);
    bin_kernel<<<256, 256, 0, stream>>>(src, dst, offs, binned, E, P, C);
    lsort_kernel<<<P, 256, 0, stream>>>(binned, rowptr, csr, N);

    // layer 1: x[N,128] @ W1 -> h (overwrites binned; build is complete); gather
    gemm_kernel<128, false><<<gemmGrid, 256, 0, stream>>>(x, W1, h, N);
    gather_kernel<<<gatherGrid, 256, 0, stream>>>(csr, rowptr, h, dinv, b1, agg, N);

    // layer 2 (relu of layer-1 output fused into gemm's X load)
    gemm_kernel<64, true><<<gemmGrid, 256, 0, stream>>>(agg, W2, h, N);
    gather_kernel<<<gatherGrid, 256, 0, stream>>>(csr, rowptr, h, dinv, b2, agg, N);

    // layer 3
    gemm_kernel<64, true><<<gemmGrid, 256, 0, stream>>>(agg, W3, h, N);
    gather_kernel<<<gatherGrid, 256, 0, stream>>>(csr, rowptr, h, dinv, b3, agg, N);

    // mean-pool per graph (+count, +fused relu) + head + softmax
    zero_kernel<<<(G * 65 + 255) / 256, 256, 0, stream>>>(sums, G * 65);
    pool_kernel<<<(N + 255) / 256, 256, 0, stream>>>(agg, batch, sums, cnts, N);
    final_kernel<<<1, 64, 0, stream>>>(sums, cnts, Wl, bl, (float*)d_out, G);
}